// Round 4
// baseline (130.238 us; speedup 1.0000x reference)
//
#include <hip/hip_runtime.h>

// ---- types ----
typedef __bf16 bf8_t  __attribute__((ext_vector_type(8)));   // 8 x bf16 = 4 VGPR (MFMA A/B frag)
typedef float  f4_t   __attribute__((ext_vector_type(4)));   // MFMA C/D frag
typedef unsigned short us4_t __attribute__((ext_vector_type(4)));

#define N_ROWS 4096
#define D_K    1024
#define TEMP_INV 20.0f   // 1 / 0.05  (folded into x-normalization)

// fp32 -> bf16, round-to-nearest-even (no NaN in this problem)
__device__ __forceinline__ unsigned short f2bf(float f) {
    unsigned int u = __builtin_bit_cast(unsigned int, f);
    u += 0x7fffu + ((u >> 16) & 1u);
    return (unsigned short)(u >> 16);
}

// async global->LDS, 16B per lane. LDS dest must be wave-uniform base + lane*16.
__device__ __forceinline__ void gl_lds16(const __bf16* g, __bf16* l) {
    __builtin_amdgcn_global_load_lds(
        (const __attribute__((address_space(1))) unsigned int*)g,
        (__attribute__((address_space(3))) unsigned int*)l,
        16, 0, 0);
}

// ---------------- fused row normalize for both inputs: v / max(||v||, eps), fp32 -> bf16 ----
// (unchanged, verified; ~7.6 us, at memory roofline for 48 MB)
__global__ __launch_bounds__(256) void norm_rows_kernel(
    const float* __restrict__ x, const float* __restrict__ y,
    unsigned short* __restrict__ xb, unsigned short* __restrict__ yb)
{
    const int b   = blockIdx.x;
    const int row = b & (N_ROWS - 1);
    const bool isx = (b < N_ROWS);
    const float* in     = isx ? x  : y;
    unsigned short* out = isx ? xb : yb;
    const float post    = isx ? TEMP_INV : 1.0f;
    const int t = threadIdx.x;
    const float4* ip = (const float4*)(in + (size_t)row * D_K);
    float4 v = ip[t];
    float ss = v.x*v.x + v.y*v.y + v.z*v.z + v.w*v.w;
    #pragma unroll
    for (int off = 32; off > 0; off >>= 1)
        ss += __shfl_down(ss, off, 64);
    __shared__ float red[4];
    if ((t & 63) == 0) red[t >> 6] = ss;
    __syncthreads();
    float tot   = red[0] + red[1] + red[2] + red[3];
    float scale = post / fmaxf(sqrtf(tot), 1e-8f);
    us4_t o;
    o.x = f2bf(v.x * scale);
    o.y = f2bf(v.y * scale);
    o.z = f2bf(v.z * scale);
    o.w = f2bf(v.w * scale);
    *(us4_t*)(out + (size_t)row * D_K + t * 4) = o;
}

// ---------------- C = A . B^T  ----------------------------------------------------------
// 256x256 tile, BK=64, 512 threads = 8 waves (2 M-halves x 4 N-quarters), per-wave 128x64 C.
//
// R4: fragment-level software pipeline INSIDE the tile (R3 post-mortem: LDS and MFMA ran
// strictly alternating — tile 6700 cyc ~= LDS floor 2690 + MFMA floor 2480 + overhead.
// Barrier count was NOT the cost: R2->R3 removed 5/8 barriers for only +5%).
// Mechanism: per tile, the next quadrant's ds_reads are issued AFTER the wait-point of the
// current quadrant but BEFORE its MFMA cluster, with no sched fence between reads and MFMAs,
// so the compiler interleaves them: reads drain on the LDS pipe under the matrix-pipe time.
//   P1: read af(q0)+bf0(q0) [12]; issue ALL 8 stages of tile t+1; lgkm(0)  <- one real wait
//   read bf1(q1) [4]   -> drains under Q(0,0) MFMA
//   Q(0,0); lgkm(0) [~free]
//   Q(0,1); read af(q1) [8, after Q01 in program order (WAR), interleaves with its issue]
//   lgkm(0) [mostly drained]; Q(1,1); Q(1,0)   [pure-register tail]
//   vmcnt(0); barrier      <- one barrier per tile; stages issued in P1 elapsed >=2/3 tile
// Two bf sets (bf0,bf1) kill the B(q0) re-read: 24 ds_read_b128/tile/wave (was 28).
// Register budget: af 32 + bf 32 + addr ~60 VGPR + 128 acc AGPR ~= 256 = 2-wave/SIMD cap.
//
// Sync ledger (single barrier per tile): reads of buf[cur] all complete before the wave's
// final lgkm(0) (pre-Q11); stages of t+1 (into buf[nxt]) complete at the wave's vmcnt(0);
// the barrier then publishes both: (a) stages(t+1) visible to all waves' reads in t+1;
// (b) all waves' reads of buf[cur] done, so stages(t+2) issued in t+1 can overwrite cur.
//
// LDS swizzle: slot (row, g) holds global 8-elem k-group g ^ (row&7); applied on the GLOBAL
// source address during staging. Fragment read start group = (quad+4*kk)^(l15&7) ->
// measured ZERO SQ_LDS_BANK_CONFLICT (R1-R3). Keep 16x16x32 MFMA (32x32 regressed).
//
// T1 XCD swizzle: 1-D grid of 256; xcd=id&7 gets bn in {2*xcd, 2*xcd+1} x all bm ->
// each XCD's 2 B-panels (1 MB) stay L2-resident; bijective remap.
__global__ __launch_bounds__(512, 2) void cosim_gemm256_kernel(
    const unsigned short* __restrict__ Aus,
    const unsigned short* __restrict__ Bus,
    float* __restrict__ C)
{
    const __bf16* A = (const __bf16*)Aus;
    const __bf16* B = (const __bf16*)Bus;

    __shared__ __align__(16) __bf16 As[2][256 * 64];   // 64 KB
    __shared__ __align__(16) __bf16 Bs[2][256 * 64];   // 64 KB

    const int t    = threadIdx.x;
    const int lane = t & 63;
    const int wid  = t >> 6;       // 0..7
    const int wm   = wid >> 2;     // 0..1   M half
    const int wn   = wid & 3;      // 0..3   N quarter
    const int l15  = lane & 15;
    const int quad = lane >> 4;

    // XCD-aware block swizzle (bijective): id = c*8 + xcd, c = hi*16 + bm, bn = xcd*2 + hi
    const int id  = blockIdx.x;
    const int xcd = id & 7;
    const int c   = id >> 3;            // 0..31
    const int bm  = c & 15;
    const int bn  = xcd * 2 + (c >> 4);

    // ---- staging constants (stager == reader partition) ----
    const int slA0 = wn * 64 + lane;          // 0..255  virtual lane over the wm-group
    const int slA1 = slA0 + 256;
    const int rA0 = slA0 >> 3, rA1 = slA1 >> 3;
    const int gA0 = (slA0 & 7) ^ (rA0 & 7);   // swizzled global k-group
    const int gA1 = (slA1 & 7) ^ (rA1 & 7);
    const unsigned gaOff0 = (unsigned)(bm * 256 + wm * 128 + rA0) * D_K + gA0 * 8;
    const unsigned gaOff1 = (unsigned)(bm * 256 + wm * 128 + rA1) * D_K + gA1 * 8;
    const int laOff0 = wm * 8192 + slA0 * 8;  // elems; + qm*4096
    const int laOff1 = wm * 8192 + slA1 * 8;
    const int slB0 = wm * 64 + lane;          // 0..127  virtual lane over the wn-group
    const int slB1 = slB0 + 128;
    const int rB0 = slB0 >> 3, rB1 = slB1 >> 3;
    const int gB0 = (slB0 & 7) ^ (rB0 & 7);
    const int gB1 = (slB1 & 7) ^ (rB1 & 7);
    const unsigned gbOff0 = (unsigned)(bn * 256 + wn * 64 + rB0) * D_K + gB0 * 8;
    const unsigned gbOff1 = (unsigned)(bn * 256 + wn * 64 + rB1) * D_K + gB1 * 8;
    const int lbOff0 = wn * 4096 + slB0 * 8;  // elems; + qn*2048
    const int lbOff1 = wn * 4096 + slB1 * 8;

#define STAGE_A(buf, qm, kelem) do { \
    gl_lds16(A + gaOff0 + (qm) * 65536 + (kelem), &As[buf][laOff0 + (qm) * 4096]); \
    gl_lds16(A + gaOff1 + (qm) * 65536 + (kelem), &As[buf][laOff1 + (qm) * 4096]); } while (0)
#define STAGE_B(buf, qn, kelem) do { \
    gl_lds16(B + gbOff0 + (qn) * 32768 + (kelem), &Bs[buf][lbOff0 + (qn) * 2048]); \
    gl_lds16(B + gbOff1 + (qn) * 32768 + (kelem), &Bs[buf][lbOff1 + (qn) * 2048]); } while (0)

    // ---- fragment read constants ----
    const int g0 = quad ^ (l15 & 7);          // kk=0 swizzled group
    const int g1 = (quad + 4) ^ (l15 & 7);    // kk=1
    const int aRd = (wm * 128 + l15) * 64;    // + qm*4096 + mi*1024 + g*8
    const int bRd = (wn * 64 + l15) * 64;     // + qn*2048 + ni*1024 + g*8

#define LDA(qm, mi, kk) (*(const bf8_t*)(&As[cur][aRd + (qm) * 4096 + (mi) * 1024 + ((kk) ? g1 : g0) * 8]))
#define LDB(qn, ni, kk) (*(const bf8_t*)(&Bs[cur][bRd + (qn) * 2048 + (ni) * 1024 + ((kk) ? g1 : g0) * 8]))

    f4_t acc[8][4];
    #pragma unroll
    for (int mi = 0; mi < 8; mi++)
        #pragma unroll
        for (int ni = 0; ni < 4; ni++) {
            acc[mi][ni][0] = 0.f; acc[mi][ni][1] = 0.f;
            acc[mi][ni][2] = 0.f; acc[mi][ni][3] = 0.f;
        }

    bf8_t af[4][2];    // A frags of current qm (4 mi x 2 kk)
    bf8_t bf0[2][2];   // B frags, q0 set
    bf8_t bf1[2][2];   // B frags, q1 set

#define RD_AF(qm) do { _Pragma("unroll") \
    for (int mi = 0; mi < 4; mi++) { af[mi][0] = LDA(qm, mi, 0); af[mi][1] = LDA(qm, mi, 1); } } while (0)
#define RD_B(SET, qn) do { _Pragma("unroll") \
    for (int ni = 0; ni < 2; ni++) { SET[ni][0] = LDB(qn, ni, 0); SET[ni][1] = LDB(qn, ni, 1); } } while (0)

#define MFMA_QUAD(QM, SET, QN) do { \
    __builtin_amdgcn_s_setprio(1); \
    _Pragma("unroll") \
    for (int mi = 0; mi < 4; mi++) \
        _Pragma("unroll") \
        for (int ni = 0; ni < 2; ni++) { \
            acc[(QM)*4+mi][(QN)*2+ni] = __builtin_amdgcn_mfma_f32_16x16x32_bf16( \
                af[mi][0], SET[ni][0], acc[(QM)*4+mi][(QN)*2+ni], 0, 0, 0); \
            acc[(QM)*4+mi][(QN)*2+ni] = __builtin_amdgcn_mfma_f32_16x16x32_bf16( \
                af[mi][1], SET[ni][1], acc[(QM)*4+mi][(QN)*2+ni], 0, 0, 0); \
        } \
    __builtin_amdgcn_s_setprio(0); } while (0)

#define FENCE_LGKM() do { \
    asm volatile("s_waitcnt lgkmcnt(0)"); \
    __builtin_amdgcn_sched_barrier(0); } while (0)

    // ---- prologue: full tile 0 into buf 0 ----
    STAGE_A(0, 0, 0); STAGE_B(0, 0, 0);
    STAGE_B(0, 1, 0); STAGE_A(0, 1, 0);
    asm volatile("s_waitcnt vmcnt(0)");
    __builtin_amdgcn_s_barrier();

    // ---- main loop: compute tile tt from buf cur; stage tile tt+1 into nxt (in P1) ----
    for (int tt = 0; tt < 16; ++tt) {
        const int cur = tt & 1;
        const int nxt = cur ^ 1;
        const int k1  = (tt + 1) * 64;

        // P1: frag reads for Q(0,*) row + ALL stages of next tile
        RD_AF(0);
        RD_B(bf0, 0);
        if (tt < 15) {
            STAGE_A(nxt, 0, k1); STAGE_B(nxt, 0, k1);
            STAGE_B(nxt, 1, k1); STAGE_A(nxt, 1, k1);
        }
        FENCE_LGKM();                     // af(q0)+bf0 resident — the one real LDS wait

        RD_B(bf1, 1);                     // drains under Q(0,0) MFMA (no fence between)
        MFMA_QUAD(0, bf0, 0);
        FENCE_LGKM();                     // bf1 resident (~free: 4 reads vs 16 MFMA)

        MFMA_QUAD(0, bf1, 1);
        RD_AF(1);                         // af(q1); interleaves with Q(0,1) issue (WAR safe)
        FENCE_LGKM();                     // af(q1) resident (mostly drained under Q(0,1))

        MFMA_QUAD(1, bf1, 1);
        MFMA_QUAD(1, bf0, 0);             // pure-register tail

        if (tt < 15) {
            asm volatile("s_waitcnt vmcnt(0)");   // stages issued >=2/3 tile ago -> ~no stall
            __builtin_amdgcn_s_barrier();
        }
    }

    // ---- C write: C/D layout col = lane&15, row = (lane>>4)*4 + reg [m89/m91 verified] ----
    #pragma unroll
    for (int mi = 0; mi < 8; mi++) {
        const int row = bm * 256 + wm * 128 + mi * 16 + quad * 4;
        #pragma unroll
        for (int ni = 0; ni < 4; ni++) {
            const int col = bn * 256 + wn * 64 + ni * 16 + l15;
            #pragma unroll
            for (int r = 0; r < 4; r++)
                C[(size_t)(row + r) * N_ROWS + col] = acc[mi][ni][r];
        }
    }

#undef STAGE_A
#undef STAGE_B
#undef LDA
#undef LDB
#undef RD_AF
#undef RD_B
#undef MFMA_QUAD
#undef FENCE_LGKM
}

extern "C" void kernel_launch(void* const* d_in, const int* in_sizes, int n_in,
                              void* d_out, int out_size, void* d_ws, size_t ws_size,
                              hipStream_t stream)
{
    const float* x = (const float*)d_in[0];
    const float* y = (const float*)d_in[1];
    float* out = (float*)d_out;

    unsigned short* xb = (unsigned short*)d_ws;                 // 8 MB
    unsigned short* yb = xb + (size_t)N_ROWS * D_K;             // 8 MB

    norm_rows_kernel<<<2 * N_ROWS, 256, 0, stream>>>(x, y, xb, yb);

    cosim_gemm256_kernel<<<dim3(256), dim3(512), 0, stream>>>(xb, yb, out);
}

// Round 5
// 122.805 us; speedup vs baseline: 1.0605x; 1.0605x over previous
//
#include <hip/hip_runtime.h>

// ---- types ----
typedef __bf16 bf8_t  __attribute__((ext_vector_type(8)));   // 8 x bf16 = 4 VGPR (MFMA A/B frag)
typedef float  f4_t   __attribute__((ext_vector_type(4)));   // MFMA C/D frag
typedef unsigned short us4_t __attribute__((ext_vector_type(4)));

#define N_ROWS 4096
#define D_K    1024
#define TEMP_INV 20.0f   // 1 / 0.05  (folded into x-normalization)

// fp32 -> bf16, round-to-nearest-even (no NaN in this problem)
__device__ __forceinline__ unsigned short f2bf(float f) {
    unsigned int u = __builtin_bit_cast(unsigned int, f);
    u += 0x7fffu + ((u >> 16) & 1u);
    return (unsigned short)(u >> 16);
}

// async global->LDS, 16B per lane. LDS dest must be wave-uniform base + lane*16.
__device__ __forceinline__ void gl_lds16(const __bf16* g, __bf16* l) {
    __builtin_amdgcn_global_load_lds(
        (const __attribute__((address_space(1))) unsigned int*)g,
        (__attribute__((address_space(3))) unsigned int*)l,
        16, 0, 0);
}

// ---------------- fused row normalize for both inputs: v / max(||v||, eps), fp32 -> bf16 ----
// (unchanged, verified; ~7.6 us, at memory roofline for 48 MB)
__global__ __launch_bounds__(256) void norm_rows_kernel(
    const float* __restrict__ x, const float* __restrict__ y,
    unsigned short* __restrict__ xb, unsigned short* __restrict__ yb)
{
    const int b   = blockIdx.x;
    const int row = b & (N_ROWS - 1);
    const bool isx = (b < N_ROWS);
    const float* in     = isx ? x  : y;
    unsigned short* out = isx ? xb : yb;
    const float post    = isx ? TEMP_INV : 1.0f;
    const int t = threadIdx.x;
    const float4* ip = (const float4*)(in + (size_t)row * D_K);
    float4 v = ip[t];
    float ss = v.x*v.x + v.y*v.y + v.z*v.z + v.w*v.w;
    #pragma unroll
    for (int off = 32; off > 0; off >>= 1)
        ss += __shfl_down(ss, off, 64);
    __shared__ float red[4];
    if ((t & 63) == 0) red[t >> 6] = ss;
    __syncthreads();
    float tot   = red[0] + red[1] + red[2] + red[3];
    float scale = post / fmaxf(sqrtf(tot), 1e-8f);
    us4_t o;
    o.x = f2bf(v.x * scale);
    o.y = f2bf(v.y * scale);
    o.z = f2bf(v.z * scale);
    o.w = f2bf(v.w * scale);
    *(us4_t*)(out + (size_t)row * D_K + t * 4) = o;
}

// ---------------- C = A . B^T  ----------------------------------------------------------
// 256x256 tile, BK=64, 512 threads = 8 waves (2 M-halves x 4 N-quarters), per-wave 128x64 C.
//
// R5: read-ahead rotation. R3/R4 post-mortem: every phase was reads->lgkm(0)->MFMA; with
// in-order per-wave issue and barrier-aligned co-waves, LDS pipe and matrix pipe strictly
// alternate -> tile time == LDS floor + MFMA floor (5100 cyc, measured). Fix: issue each
// read batch BEFORE the preceding MFMA cluster in program order; its lgkmcnt(0) lands
// after that cluster, so reads drain while MFMAs issue. Cross-tile: q00 frags of tile t+1
// are read before tile t's LAST cluster (buf[nxt] published by the mid-tile vmcnt+barrier),
// so every tile begins with MFMA, never with a serial read block.
//
// Per-tile schedule (steady state; entry: 12 reads {afX=af(q0),b0=b0(q0)} outstanding):
//   STAGE 8 -> buf[nxt]                      (tile t+1; vm only)
//   lgkm(0)          <- waits entry reads; they drained under prev tile's Q10
//   RD bf1 (4, buf[cur]) ; SB0 ; Q00(afX,b0)
//   lgkm(0) ; RD afY (8, buf[cur]) ; SB0 ; Q01(afX,bf1)        afX dead
//   lgkm(0) ;                        Q11(afY,bf1)              bf1 dead
//   vmcnt(0) ; barrier   <- publishes buf[nxt]; all buf[cur] reads were before this
//   RD afX (8, buf[nxt]) ; SB0 ; Q10(afY,b0)                   afY,b0 dead after
//   SB0 ; RD b0 (4, buf[nxt])      <- after Q10 (single b0 set; ~50cyc at next fence)
// One barrier/tile; stages get ~1800 cyc before their vmcnt(0).
// Buffer safety: after tile t-1's barrier no wave reads buf[cur of t-1] again (last such
// read is afY, before that barrier) -> tile t's STAGE into it is race-free.
//
// Regs: afX 32 + afY 32 + b0 16 + bf1 16 = 96 frag VGPR + acc 128 AGPR; watch VGPR_Count.
//
// LDS swizzle: slot (row, g) holds global 8-elem k-group g ^ (row&7); applied on the
// GLOBAL source address during staging. Fragment read start group = (quad+4*kk)^(l15&7)
// -> measured ZERO SQ_LDS_BANK_CONFLICT (R1-R4). Keep 16x16x32 MFMA (32x32 regressed).
// Grid: plain 2-D (XCD swizzle measured null on FETCH in R4 - inputs are L2/L3-resident).
__global__ __launch_bounds__(512, 2) void cosim_gemm256_kernel(
    const unsigned short* __restrict__ Aus,
    const unsigned short* __restrict__ Bus,
    float* __restrict__ C)
{
    const __bf16* A = (const __bf16*)Aus;
    const __bf16* B = (const __bf16*)Bus;

    __shared__ __align__(16) __bf16 As[2][256 * 64];   // 64 KB
    __shared__ __align__(16) __bf16 Bs[2][256 * 64];   // 64 KB

    const int t    = threadIdx.x;
    const int lane = t & 63;
    const int wid  = t >> 6;       // 0..7
    const int wm   = wid >> 2;     // 0..1   M half
    const int wn   = wid & 3;      // 0..3   N quarter
    const int bm   = blockIdx.x;
    const int bn   = blockIdx.y;
    const int l15  = lane & 15;
    const int quad = lane >> 4;

    // ---- staging constants (stager == reader partition) ----
    const int slA0 = wn * 64 + lane;          // 0..255  virtual lane over the wm-group
    const int slA1 = slA0 + 256;
    const int rA0 = slA0 >> 3, rA1 = slA1 >> 3;
    const int gA0 = (slA0 & 7) ^ (rA0 & 7);   // swizzled global k-group
    const int gA1 = (slA1 & 7) ^ (rA1 & 7);
    const unsigned gaOff0 = (unsigned)(bm * 256 + wm * 128 + rA0) * D_K + gA0 * 8;
    const unsigned gaOff1 = (unsigned)(bm * 256 + wm * 128 + rA1) * D_K + gA1 * 8;
    const int laOff0 = wm * 8192 + slA0 * 8;  // elems; + qm*4096
    const int laOff1 = wm * 8192 + slA1 * 8;
    const int slB0 = wm * 64 + lane;          // 0..127  virtual lane over the wn-group
    const int slB1 = slB0 + 128;
    const int rB0 = slB0 >> 3, rB1 = slB1 >> 3;
    const int gB0 = (slB0 & 7) ^ (rB0 & 7);
    const int gB1 = (slB1 & 7) ^ (rB1 & 7);
    const unsigned gbOff0 = (unsigned)(bn * 256 + wn * 64 + rB0) * D_K + gB0 * 8;
    const unsigned gbOff1 = (unsigned)(bn * 256 + wn * 64 + rB1) * D_K + gB1 * 8;
    const int lbOff0 = wn * 4096 + slB0 * 8;  // elems; + qn*2048
    const int lbOff1 = wn * 4096 + slB1 * 8;

#define STAGE_ALL(buf, kelem) do { \
    gl_lds16(A + gaOff0 + (kelem),         &As[buf][laOff0]); \
    gl_lds16(A + gaOff1 + (kelem),         &As[buf][laOff1]); \
    gl_lds16(B + gbOff0 + (kelem),         &Bs[buf][lbOff0]); \
    gl_lds16(B + gbOff1 + (kelem),         &Bs[buf][lbOff1]); \
    gl_lds16(B + gbOff0 + 32768 + (kelem), &Bs[buf][lbOff0 + 2048]); \
    gl_lds16(B + gbOff1 + 32768 + (kelem), &Bs[buf][lbOff1 + 2048]); \
    gl_lds16(A + gaOff0 + 65536 + (kelem), &As[buf][laOff0 + 4096]); \
    gl_lds16(A + gaOff1 + 65536 + (kelem), &As[buf][laOff1 + 4096]); } while (0)

    // ---- fragment read constants ----
    const int g0 = quad ^ (l15 & 7);          // kk=0 swizzled group
    const int g1 = (quad + 4) ^ (l15 & 7);    // kk=1
    const int aRd = (wm * 128 + l15) * 64;    // + qm*4096 + mi*1024 + g*8
    const int bRd = (wn * 64 + l15) * 64;     // + qn*2048 + ni*1024 + g*8

#define RD_AF(SET, BUF, qm) do { _Pragma("unroll") \
    for (int mi = 0; mi < 4; mi++) { \
        SET[mi][0] = *(const bf8_t*)(&As[BUF][aRd + (qm) * 4096 + mi * 1024 + g0 * 8]); \
        SET[mi][1] = *(const bf8_t*)(&As[BUF][aRd + (qm) * 4096 + mi * 1024 + g1 * 8]); } } while (0)
#define RD_B(SET, BUF, qn) do { _Pragma("unroll") \
    for (int ni = 0; ni < 2; ni++) { \
        SET[ni][0] = *(const bf8_t*)(&Bs[BUF][bRd + (qn) * 2048 + ni * 1024 + g0 * 8]); \
        SET[ni][1] = *(const bf8_t*)(&Bs[BUF][bRd + (qn) * 2048 + ni * 1024 + g1 * 8]); } } while (0)

    f4_t acc[8][4];
    #pragma unroll
    for (int mi = 0; mi < 8; mi++)
        #pragma unroll
        for (int ni = 0; ni < 4; ni++) {
            acc[mi][ni][0] = 0.f; acc[mi][ni][1] = 0.f;
            acc[mi][ni][2] = 0.f; acc[mi][ni][3] = 0.f;
        }

    bf8_t afX[4][2];   // af(q0) of current tile / prefetch target for next tile
    bf8_t afY[4][2];   // af(q1) of current tile
    bf8_t b0[2][2];    // b(q0): live whole tile (Q00 + Q10); reloaded after Q10
    bf8_t bf1[2][2];   // b(q1): Q01 + Q11

#define MFMA_QUAD(AF, BF, QM, QN) do { \
    __builtin_amdgcn_s_setprio(1); \
    _Pragma("unroll") \
    for (int mi = 0; mi < 4; mi++) \
        _Pragma("unroll") \
        for (int ni = 0; ni < 2; ni++) { \
            acc[(QM)*4+mi][(QN)*2+ni] = __builtin_amdgcn_mfma_f32_16x16x32_bf16( \
                AF[mi][0], BF[ni][0], acc[(QM)*4+mi][(QN)*2+ni], 0, 0, 0); \
            acc[(QM)*4+mi][(QN)*2+ni] = __builtin_amdgcn_mfma_f32_16x16x32_bf16( \
                AF[mi][1], BF[ni][1], acc[(QM)*4+mi][(QN)*2+ni], 0, 0, 0); \
        } \
    __builtin_amdgcn_s_setprio(0); } while (0)

#define FENCE_LGKM() do { \
    asm volatile("s_waitcnt lgkmcnt(0)"); \
    __builtin_amdgcn_sched_barrier(0); } while (0)
#define SB0() __builtin_amdgcn_sched_barrier(0)

// One tile. Entry: 12 reads (afX q0 + b0 q0 of this tile) outstanding. CUR/NXT compile-time.
#define TILE_BODY(TT, CUR, NXT) do { \
    if ((TT) < 15) STAGE_ALL(NXT, ((TT) + 1) * 64); \
    FENCE_LGKM();                    /* entry reads done (drained under prev Q10) */ \
    RD_B(bf1, CUR, 1); SB0(); \
    MFMA_QUAD(afX, b0, 0, 0);        /* Q00; bf1 drains underneath */ \
    FENCE_LGKM(); \
    RD_AF(afY, CUR, 1); SB0(); \
    MFMA_QUAD(afX, bf1, 0, 1);       /* Q01; afY drains underneath; afX dead */ \
    FENCE_LGKM(); \
    MFMA_QUAD(afY, bf1, 1, 1);       /* Q11; bf1 dead */ \
    if ((TT) < 15) { \
        asm volatile("s_waitcnt vmcnt(0)");   /* stages issued ~3 clusters ago */ \
        __builtin_amdgcn_s_barrier();         /* publish buf[NXT]; cur reads all done */ \
        RD_AF(afX, NXT, 0); SB0(); \
    } \
    MFMA_QUAD(afY, b0, 1, 0);        /* Q10; next-afX drains underneath; afY,b0 dead */ \
    if ((TT) < 15) { SB0(); RD_B(b0, NXT, 0); }  /* reuse b0 regs (dead after Q10) */ \
} while (0)

    // ---- prologue: stage tile 0, publish, issue q00 frag reads ----
    STAGE_ALL(0, 0);
    asm volatile("s_waitcnt vmcnt(0)");
    __builtin_amdgcn_s_barrier();
    RD_AF(afX, 0, 0);
    RD_B(b0, 0, 0);        // 12 outstanding -> entry invariant

    // ---- main loop: 2-tile unroll keeps buffer indices compile-time ----
    for (int tt = 0; tt < 16; tt += 2) {
        TILE_BODY(tt,     0, 1);
        TILE_BODY(tt + 1, 1, 0);
    }

    // ---- C write: C/D layout col = lane&15, row = (lane>>4)*4 + reg [m89/m91 verified] ----
    #pragma unroll
    for (int mi = 0; mi < 8; mi++) {
        const int row = bm * 256 + wm * 128 + mi * 16 + quad * 4;
        #pragma unroll
        for (int ni = 0; ni < 4; ni++) {
            const int col = bn * 256 + wn * 64 + ni * 16 + l15;
            #pragma unroll
            for (int r = 0; r < 4; r++)
                C[(size_t)(row + r) * N_ROWS + col] = acc[mi][ni][r];
        }
    }

#undef STAGE_ALL
#undef RD_AF
#undef RD_B
#undef MFMA_QUAD
#undef FENCE_LGKM
#undef SB0
#undef TILE_BODY
}

extern "C" void kernel_launch(void* const* d_in, const int* in_sizes, int n_in,
                              void* d_out, int out_size, void* d_ws, size_t ws_size,
                              hipStream_t stream)
{
    const float* x = (const float*)d_in[0];
    const float* y = (const float*)d_in[1];
    float* out = (float*)d_out;

    unsigned short* xb = (unsigned short*)d_ws;                 // 8 MB
    unsigned short* yb = xb + (size_t)N_ROWS * D_K;             // 8 MB

    norm_rows_kernel<<<2 * N_ROWS, 256, 0, stream>>>(x, y, xb, yb);

    dim3 grid(N_ROWS / 256, N_ROWS / 256);                      // 16x16 = 256 blocks, 1/CU
    cosim_gemm256_kernel<<<grid, 512, 0, stream>>>(xb, yb, out);
}